// Round 4
// baseline (158.246 us; speedup 1.0000x reference)
//
#include <hip/hip_runtime.h>
#include <hip/hip_bf16.h>

#define HW 16384   // 128*128
#define CC 64
#define BB 4

typedef __attribute__((ext_vector_type(8))) short bf8;   // 8 bf16 (4 VGPRs)
typedef __attribute__((ext_vector_type(4))) float f4;    // MFMA C/D frag

static __device__ __forceinline__ float bf2f(unsigned short u) {
    return __uint_as_float(((unsigned)u) << 16);
}
static __device__ __forceinline__ unsigned short f2bf(float f) {
    __hip_bfloat16 h = __float2bfloat16(f);   // RNE
    return *reinterpret_cast<unsigned short*>(&h);
}

// ---------------------------------------------------------------------------
// K0 (merged prep + transpose):
//  blocks [0,216):   wA[32][576], Wal[64][576] bf16 weight repack
//  blocks [216,472): xT[b*HW+hw][c] bf16 (channels contiguous, 128B rows)
// ---------------------------------------------------------------------------
__global__ __launch_bounds__(256) void k_prep_tx(const float* __restrict__ x,
                                                 const float* __restrict__ w_off,
                                                 const float* __restrict__ w_align,
                                                 unsigned short* __restrict__ xT,
                                                 unsigned short* __restrict__ wA,
                                                 unsigned short* __restrict__ Wal) {
    int bx = blockIdx.x;
    if (bx < 216) {
        int i = bx * 256 + threadIdx.x;
        if (i < 32 * 576) {
            int m = i / 576, r = i - m * 576, t = r >> 6, c = r & 63;
            float v = (m < 27) ? w_off[m * 576 + c * 9 + t] : 0.f;
            wA[i] = f2bf(v);
        } else {
            int j = i - 32 * 576;   // j < 64*576 by grid construction
            int o = j / 576, r = j - o * 576, t = r >> 6, c = r & 63;
            Wal[j] = f2bf(w_align[o * 576 + c * 9 + t]);
        }
    } else {
        int idx = (bx - 216) * 256 + threadIdx.x;      // b*HW + hw
        const float* xp = x + (size_t)(idx >> 14) * CC * HW + (idx & (HW - 1));
        unsigned short* op = xT + (size_t)idx * CC;
#pragma unroll
        for (int c8 = 0; c8 < 8; c8++) {
            unsigned short u[8];
#pragma unroll
            for (int j = 0; j < 8; j++) u[j] = f2bf(xp[(size_t)(c8 * 8 + j) * HW]);
            uint4 q;
            q.x = u[0] | ((unsigned)u[1] << 16);
            q.y = u[2] | ((unsigned)u[3] << 16);
            q.z = u[4] | ((unsigned)u[5] << 16);
            q.w = u[6] | ((unsigned)u[7] << 16);
            *(uint4*)(op + c8 * 8) = q;
        }
    }
}

// ---------------------------------------------------------------------------
// K1: offset conv as 9-tap shifted MFMA GEMM. M=32 (27 used), K=576, N=65536.
// All 18 B-fragments staged into registers BEFORE the MFMA chain so the
// 18 global_load_dwordx4 are all in flight together (latency overlap).
// ---------------------------------------------------------------------------
__global__ __launch_bounds__(256) void k_conv(const unsigned short* __restrict__ xT,
                                              const unsigned short* __restrict__ wA,
                                              const float* __restrict__ b_off,
                                              float* __restrict__ off) {
    int t = threadIdx.x, lane = t & 63, wv = t >> 6;
    int quad = lane >> 4, col = lane & 15;
    int n = blockIdx.x * 64 + wv * 16 + col;           // global pixel
    int b = n >> 14, hw = n & (HW - 1), h = hw >> 7, w = hw & 127;
    const unsigned short* xTb = xT + (size_t)b * HW * CC;
    const bf8 zero = {0, 0, 0, 0, 0, 0, 0, 0};

    // ---- stage all 18 B-fragments (9 taps x 2 c-halves) ----
    bf8 bfr[18];
#pragma unroll
    for (int tap = 0; tap < 9; tap++) {
        int dyt = tap / 3 - 1, dxt = tap - (tap / 3) * 3 - 1;
        int hs = h + dyt, ws = w + dxt;
        bool valid = ((unsigned)hs < 128u) && ((unsigned)ws < 128u);
        int hc = min(max(hs, 0), 127), wc = min(max(ws, 0), 127);
        const unsigned short* src = xTb + ((size_t)(hc * 128 + wc)) * CC + quad * 8;
        bfr[2 * tap]     = *(const bf8*)(src);
        bfr[2 * tap + 1] = *(const bf8*)(src + 32);
        if (!valid) { bfr[2 * tap] = zero; bfr[2 * tap + 1] = zero; }
    }

    f4 acc0 = {0.f, 0.f, 0.f, 0.f};
    f4 acc1 = {0.f, 0.f, 0.f, 0.f};
#pragma unroll
    for (int s = 0; s < 18; s++) {
        int tap = s >> 1, c0 = (s & 1) << 5;
        bf8 a0 = *(const bf8*)(wA + (size_t)col * 576 + tap * 64 + c0 + quad * 8);
        bf8 a1 = *(const bf8*)(wA + (size_t)(col + 16) * 576 + tap * 64 + c0 + quad * 8);
        acc0 = __builtin_amdgcn_mfma_f32_16x16x32_bf16(a0, bfr[s], acc0, 0, 0, 0);
        acc1 = __builtin_amdgcn_mfma_f32_16x16x32_bf16(a1, bfr[s], acc1, 0, 0, 0);
    }
#pragma unroll
    for (int i = 0; i < 4; i++) {
        int o0 = quad * 4 + i;                          // 0..15, always < 27
        {
            float v = acc0[i] + b_off[o0];
            if (o0 >= 18) v = 2.f / (1.f + __expf(-v));
            off[((size_t)b * 27 + o0) * HW + hw] = v;
        }
        int o1 = 16 + o0;
        if (o1 < 27) {
            float v = acc1[i] + b_off[o1];
            if (o1 >= 18) v = 2.f / (1.f + __expf(-v));
            off[((size_t)b * 27 + o1) * HW + hw] = v;
        }
    }
}

// ---------------------------------------------------------------------------
// K2 (fused): sampling -> LDS -> einsum MFMA -> exp(sigmoid) -> wten.
// Block = 256 threads / 32 pixels. Phase A issues gathers in 3-tap batches
// (12 dwordx4 in flight per thread) to overlap L2 latency.
// ---------------------------------------------------------------------------
__global__ __launch_bounds__(256) void k_fused(const unsigned short* __restrict__ xT,
                                               const float* __restrict__ off,
                                               const unsigned short* __restrict__ Wal,
                                               const float* __restrict__ b_align,
                                               float* __restrict__ wten) {
    __shared__ unsigned short S2[2304 * 8];   // 36864 B
    __shared__ float offL[27][32];            // 3456 B

    int t = threadIdx.x, lane = t & 63, wv = t >> 6;
    int n0 = blockIdx.x * 32;                 // global pixel base
    int b = n0 >> 14, hw0 = n0 & (HW - 1);
    const unsigned short* xTb = xT + (size_t)b * HW * CC;

    // ---- stage offsets ----
    for (int i = t; i < 27 * 32; i += 256) {
        int r = i >> 5, p = i & 31;
        offL[r][p] = off[((size_t)b * 27 + r) * HW + hw0 + p];
    }
    __syncthreads();

    // ---- phase A: sampling into LDS, 3-tap load batches ----
    {
        int cg = lane & 7;
        int p  = wv * 8 + (lane >> 3);
        int hw = hw0 + p, h = hw >> 7, w = hw & 127;
        const unsigned short* base = xTb + cg * 8;
#pragma unroll
        for (int kb = 0; kb < 9; kb += 3) {
            uint4 q[3][4];
            float cw[3][4];
#pragma unroll
            for (int kk = 0; kk < 3; kk++) {
                int k = kb + kk;
                float dy = offL[2 * k][p];
                float dx = offL[2 * k + 1][p];
                float m  = offL[18 + k][p];
                int k3 = k / 3;
                float ys = (float)(h + k3 - 1) + dy;
                float xs = (float)(w + (k - 3 * k3) - 1) + dx;
                float y0f = floorf(ys), x0f = floorf(xs);
                float fy = ys - y0f, fx = xs - x0f;
                int y0 = (int)y0f, x0 = (int)x0f;
                int y1 = y0 + 1, x1 = x0 + 1;
                bool vy0 = (unsigned)y0 < 128u, vy1 = (unsigned)y1 < 128u;
                bool vx0 = (unsigned)x0 < 128u, vx1 = (unsigned)x1 < 128u;
                int cy0 = min(max(y0, 0), 127), cy1 = min(max(y1, 0), 127);
                int cx0 = min(max(x0, 0), 127), cx1 = min(max(x1, 0), 127);
                cw[kk][0] = (1.f - fy) * (1.f - fx) * ((vy0 && vx0) ? m : 0.f);
                cw[kk][1] = (1.f - fy) * fx         * ((vy0 && vx1) ? m : 0.f);
                cw[kk][2] = fy * (1.f - fx)         * ((vy1 && vx0) ? m : 0.f);
                cw[kk][3] = fy * fx                 * ((vy1 && vx1) ? m : 0.f);
                q[kk][0] = *(const uint4*)(base + ((size_t)(cy0 * 128 + cx0)) * CC);
                q[kk][1] = *(const uint4*)(base + ((size_t)(cy0 * 128 + cx1)) * CC);
                q[kk][2] = *(const uint4*)(base + ((size_t)(cy1 * 128 + cx0)) * CC);
                q[kk][3] = *(const uint4*)(base + ((size_t)(cy1 * 128 + cx1)) * CC);
            }
#pragma unroll
            for (int kk = 0; kk < 3; kk++) {
                int k = kb + kk;
                const unsigned short* u00 = (const unsigned short*)&q[kk][0];
                const unsigned short* u01 = (const unsigned short*)&q[kk][1];
                const unsigned short* u10 = (const unsigned short*)&q[kk][2];
                const unsigned short* u11 = (const unsigned short*)&q[kk][3];
                unsigned short ov[8];
#pragma unroll
                for (int j = 0; j < 8; j++) {
                    float v = cw[kk][0] * bf2f(u00[j]) + cw[kk][1] * bf2f(u01[j])
                            + cw[kk][2] * bf2f(u10[j]) + cw[kk][3] * bf2f(u11[j]);
                    ov[j] = f2bf(v);
                }
                uint4 qq;
                qq.x = ov[0] | ((unsigned)ov[1] << 16);
                qq.y = ov[2] | ((unsigned)ov[3] << 16);
                qq.z = ov[4] | ((unsigned)ov[5] << 16);
                qq.w = ov[6] | ((unsigned)ov[7] << 16);
                *(uint4*)(S2 + ((size_t)((k * 8 + cg) * 32 + p)) * 8) = qq;
            }
        }
    }
    __syncthreads();

    // ---- phase B: einsum MFMA ----
    {
        int quad = lane >> 4, col = lane & 15;
        int pg = wv & 1, mh = wv >> 1;
        int pp = pg * 16 + col;
        f4 acc0 = {0.f, 0.f, 0.f, 0.f};
        f4 acc1 = {0.f, 0.f, 0.f, 0.f};
        const unsigned short* wrow = Wal + (size_t)(mh * 32 + col) * 576 + quad * 8;
#pragma unroll
        for (int s = 0; s < 18; s++) {
            int k = s >> 1, cgc = ((s & 1) << 2) + quad;
            bf8 bfrag = *(const bf8*)(S2 + ((size_t)((k * 8 + cgc) * 32 + pp)) * 8);
            bf8 a0 = *(const bf8*)(wrow + s * 32);
            bf8 a1 = *(const bf8*)(wrow + (size_t)16 * 576 + s * 32);
            acc0 = __builtin_amdgcn_mfma_f32_16x16x32_bf16(a0, bfrag, acc0, 0, 0, 0);
            acc1 = __builtin_amdgcn_mfma_f32_16x16x32_bf16(a1, bfrag, acc1, 0, 0, 0);
        }
#pragma unroll
        for (int i = 0; i < 4; i++) {
            {
                int o = mh * 32 + quad * 4 + i;
                float u = acc0[i] + b_align[o];
                float sg = 1.f / (1.f + __expf(-u));
                wten[((size_t)b * CC + o) * HW + hw0 + pp] = __expf(sg);
            }
            {
                int o = mh * 32 + 16 + quad * 4 + i;
                float u = acc1[i] + b_align[o];
                float sg = 1.f / (1.f + __expf(-u));
                wten[((size_t)b * CC + o) * HW + hw0 + pp] = __expf(sg);
            }
        }
    }
}

// ---------------------------------------------------------------------------
// K3: out = pool3s2(w*x)/pool3s2(w) (the /9 cancels; zero-pad taps drop out).
// ---------------------------------------------------------------------------
__global__ __launch_bounds__(256) void k_pool(const float* __restrict__ x,
                                              const float* __restrict__ wten,
                                              float* __restrict__ out) {
    int idx = blockIdx.x * 256 + threadIdx.x;
    int ow = idx & 63;
    int oh = (idx >> 6) & 63;
    int bc = idx >> 12;
    const float* wp = wten + (size_t)bc * HW;
    const float* xp = x + (size_t)bc * HW;
    float num = 0.f, den = 0.f;
#pragma unroll
    for (int iy = 0; iy < 3; iy++) {
        int y = 2 * oh + iy - 1;
        if ((unsigned)y >= 128u) continue;
#pragma unroll
        for (int ix = 0; ix < 3; ix++) {
            int xc = 2 * ow + ix - 1;
            if ((unsigned)xc >= 128u) continue;
            float wv = wp[y * 128 + xc];
            float xv = xp[y * 128 + xc];
            num = fmaf(wv, xv, num);
            den += wv;
        }
    }
    out[idx] = num / den;
}

// ---------------------------------------------------------------------------
extern "C" void kernel_launch(void* const* d_in, const int* in_sizes, int n_in,
                              void* d_out, int out_size, void* d_ws, size_t ws_size,
                              hipStream_t stream) {
    const float* x       = (const float*)d_in[0];
    const float* w_off   = (const float*)d_in[1];
    const float* b_off   = (const float*)d_in[2];
    const float* w_align = (const float*)d_in[3];
    const float* b_align = (const float*)d_in[4];
    float* out = (float*)d_out;

    // workspace layout (~32.4 MB):
    char* p = (char*)d_ws;
    float* off  = (float*)p;                  p += (size_t)BB * 27 * HW * 4;  // 7.08 MB
    float* wten = (float*)p;                  p += (size_t)BB * CC * HW * 4;  // 16.78 MB
    unsigned short* xT  = (unsigned short*)p; p += (size_t)BB * HW * CC * 2;  // 8.39 MB
    unsigned short* wA  = (unsigned short*)p; p += 32 * 576 * 2;              // 36.9 KB
    unsigned short* Wal = (unsigned short*)p;                                 // 73.7 KB

    k_prep_tx<<<dim3(472), dim3(256), 0, stream>>>(x, w_off, w_align, xT, wA, Wal);
    k_conv<<<dim3(1024), dim3(256), 0, stream>>>(xT, wA, b_off, off);
    k_fused<<<dim3(2048), dim3(256), 0, stream>>>(xT, off, Wal, b_align, wten);
    k_pool<<<dim3(4096), dim3(256), 0, stream>>>(x, wten, out);
}